// Round 2
// baseline (1401.860 us; speedup 1.0000x reference)
//
#include <hip/hip_runtime.h>
#include <hip/hip_bf16.h>

#define N_TOK 8192
#define D_IN  2048
#define D_OUT 8192
#define NEXP  8
#define BM    256
#define BN    256
#define BK    64
#define NTILE_MAX 40
#define YSTRIPS   (D_OUT / BN)        /* 32 */
#define GRID      (NTILE_MAX * YSTRIPS) /* 1280 = 8*160 */
#define KSTEPS    (D_IN / BK)         /* 32 */

// ws layout (int units):
// [0] num_tiles; [8..48) tile_expert; [96..136) tile_row_start;
// [192..232) tile_rows; [512..512+N) order (token ids grouped by expert)

typedef float  f32x4  __attribute__((ext_vector_type(4)));
typedef __bf16 bf16x8 __attribute__((ext_vector_type(8)));

__global__ void SwitchLinear_setup_kernel(const int* __restrict__ idx,
                                          int* __restrict__ ws) {
    __shared__ int cnt[NEXP], cur[NEXP];
    int t = threadIdx.x;
    if (t < NEXP) cnt[t] = 0;
    __syncthreads();
    for (int i = t; i < N_TOK; i += 256) atomicAdd(&cnt[idx[i]], 1);
    __syncthreads();
    if (t == 0) {
        int o = 0, nt = 0;
        for (int e = 0; e < NEXP; ++e) {
            cur[e] = o;
            int c = cnt[e];
            for (int r = 0; r < c; r += BM) {
                ws[8 + nt]   = e;
                ws[96 + nt]  = o + r;
                ws[192 + nt] = (c - r < BM) ? (c - r) : BM;
                ++nt;
            }
            o += c;
        }
        ws[0] = nt;
    }
    __syncthreads();
    for (int i = t; i < N_TOK; i += 256) {
        int p = atomicAdd(&cur[idx[i]], 1);
        ws[512 + p] = i;
    }
}

// unified XOR swizzle: 128-B rows, 16-B slots, slot index mixes row bits 0-2 and 3-5
__device__ __forceinline__ int sw_byte(int r, int kbyte) {
    int slot = (r ^ (r >> 3)) & 7;
    return r * 128 + (kbyte ^ (slot << 4));
}

__global__ __launch_bounds__(512, 2) void SwitchLinear_gemm_kernel(
    const float* __restrict__ x, const float* __restrict__ w,
    const int* __restrict__ ws, float* __restrict__ out) {
    const int nt = ws[0];
    // XCD-bijective swizzle: 160 consecutive logical blocks per XCD,
    // logical order y-fastest (same A-tile shared by 32 consecutive logicals)
    const int bid = blockIdx.x;
    const int lb  = (bid & 7) * (GRID / 8) + (bid >> 3);
    const int tx  = lb >> 5;          // row tile
    const int y   = lb & 31;          // col strip
    if (tx >= nt) return;
    const int e    = ws[8 + tx];
    const int rs   = ws[96 + tx];
    const int rows = ws[192 + tx];
    const int col0 = y * BN;

    __shared__ __align__(16) unsigned short As[2][BM * BK];
    __shared__ __align__(16) unsigned short Bs[2][BN * BK];
    __shared__ int ord[BM];

    const int t = threadIdx.x;
    {
        int rr = (t < rows) ? (rs + t) : rs;
        if (t < BM) ord[t] = ws[512 + rr];
    }
    __syncthreads();

    // ---- A staging plan: chunk c = t + 512*i (i<8): row=c>>4, kq=c&15
    const int kq = t & 15;
    const int r0 = t >> 4;            // rows r0 + 32*i
    int offA[8];                      // byte offsets into x (32-bit, max 64MB)
#pragma unroll
    for (int i = 0; i < 8; ++i)
        offA[i] = ord[r0 + 32 * i] * (D_IN * 4) + kq * 16;
    // ---- B staging plan: micro-tile mt = t + 512*i (i<2): kg=mt>>6, q=mt&63
    const int qB  = t & 63;
    const int kg0 = t >> 6;           // k-groups kg0 + 8*i
    long offB[2];                     // byte offsets into w (needs 64-bit: up to 512MB)
#pragma unroll
    for (int i = 0; i < 2; ++i)
        offB[i] = (long)e * (D_IN * (long)D_OUT * 4) +
                  (long)((kg0 + 8 * i) * 4) * (D_OUT * 4) + (col0 + qB * 4) * 4;

    const int lane = t & 63;
    const int wid  = t >> 6;
    const int wr = wid >> 2, wc = wid & 3;   // 2 x 4 wave grid
    const int lm = lane & 15, lk = lane >> 4;

    f32x4 acc[8][4];
#pragma unroll
    for (int i = 0; i < 8; ++i)
#pragma unroll
        for (int j = 0; j < 4; ++j) acc[i][j] = (f32x4){0.f, 0.f, 0.f, 0.f};

    f32x4 rA[8];
    f32x4 rB[2][4];

#define LOAD_TILE(tt)                                                          \
    {                                                                          \
        const int k0b = (tt) * (BK * 4);                                       \
        _Pragma("unroll")                                                      \
        for (int i = 0; i < 8; ++i)                                            \
            rA[i] = *(const f32x4*)((const char*)x + offA[i] + k0b);           \
        _Pragma("unroll")                                                      \
        for (int i = 0; i < 2; ++i) {                                          \
            const char* p = (const char*)w + offB[i] + (long)(tt) * (BK * 4) * D_OUT; \
            _Pragma("unroll")                                                  \
            for (int j = 0; j < 4; ++j)                                        \
                rB[i][j] = *(const f32x4*)(p + (long)j * (D_OUT * 4));         \
        }                                                                      \
    }

#define WRITE_TILE(buf)                                                        \
    {                                                                          \
        _Pragma("unroll")                                                      \
        for (int i = 0; i < 8; ++i) {                                          \
            union { __bf16 h[4]; uint2 u; } c;                                 \
            c.h[0] = (__bf16)rA[i][0]; c.h[1] = (__bf16)rA[i][1];              \
            c.h[2] = (__bf16)rA[i][2]; c.h[3] = (__bf16)rA[i][3];              \
            *(uint2*)((char*)As[buf] + sw_byte(r0 + 32 * i, kq * 8)) = c.u;    \
        }                                                                      \
        _Pragma("unroll")                                                      \
        for (int i = 0; i < 2; ++i) {                                          \
            const int kg = kg0 + 8 * i;                                        \
            _Pragma("unroll")                                                  \
            for (int j2 = 0; j2 < 4; ++j2) {                                   \
                union { __bf16 h[4]; uint2 u; } c;                             \
                c.h[0] = (__bf16)rB[i][0][j2]; c.h[1] = (__bf16)rB[i][1][j2];  \
                c.h[2] = (__bf16)rB[i][2][j2]; c.h[3] = (__bf16)rB[i][3][j2];  \
                *(uint2*)((char*)Bs[buf] + sw_byte(qB * 4 + j2, kg * 8)) = c.u;\
            }                                                                  \
        }                                                                      \
    }

#define COMPUTE_TILE(buf)                                                      \
    {                                                                          \
        _Pragma("unroll")                                                      \
        for (int ks = 0; ks < 2; ++ks) {                                       \
            const int kbyte = ks * 64 + lk * 16;                               \
            bf16x8 b[4];                                                       \
            _Pragma("unroll")                                                  \
            for (int ni = 0; ni < 4; ++ni)                                     \
                b[ni] = *(const bf16x8*)((const char*)Bs[buf] +                \
                          sw_byte(wc * 64 + ni * 16 + lm, kbyte));             \
            _Pragma("unroll")                                                  \
            for (int half = 0; half < 2; ++half) {                             \
                bf16x8 a[4];                                                   \
                _Pragma("unroll")                                              \
                for (int q = 0; q < 4; ++q)                                    \
                    a[q] = *(const bf16x8*)((const char*)As[buf] +             \
                              sw_byte(wr * 128 + (half * 4 + q) * 16 + lm, kbyte)); \
                __builtin_amdgcn_s_setprio(1);                                 \
                _Pragma("unroll")                                              \
                for (int q = 0; q < 4; ++q)                                    \
                    _Pragma("unroll")                                          \
                    for (int ni = 0; ni < 4; ++ni)                             \
                        acc[half * 4 + q][ni] =                                \
                            __builtin_amdgcn_mfma_f32_16x16x32_bf16(           \
                                a[q], b[ni], acc[half * 4 + q][ni], 0, 0, 0);  \
                __builtin_amdgcn_s_setprio(0);                                 \
            }                                                                  \
        }                                                                      \
    }

    // prologue
    LOAD_TILE(0);
    WRITE_TILE(0);
    LOAD_TILE(1);
    __syncthreads();

    for (int kt = 0; kt < KSTEPS; ++kt) {
        const int cur = kt & 1;
        COMPUTE_TILE(cur);
        if (kt == KSTEPS - 1) break;
        WRITE_TILE(cur ^ 1);          // consumes in-flight regs for tile kt+1
        if (kt + 2 < KSTEPS) LOAD_TILE(kt + 2);
        __syncthreads();
    }

    // epilogue: C/D layout col=lane&15, row=(lane>>4)*4+reg
#pragma unroll
    for (int mi = 0; mi < 8; ++mi) {
#pragma unroll
        for (int j = 0; j < 4; ++j) {
            int rl = wr * 128 + mi * 16 + lk * 4 + j;
            if (rl < rows) {
                int token = ord[rl];
                float* po = out + (long)token * D_OUT + col0 + wc * 64 + lm;
#pragma unroll
                for (int ni = 0; ni < 4; ++ni) po[ni * 16] = acc[mi][ni][j];
            }
        }
    }
}

extern "C" void kernel_launch(void* const* d_in, const int* in_sizes, int n_in,
                              void* d_out, int out_size, void* d_ws, size_t ws_size,
                              hipStream_t stream) {
    const float* x   = (const float*)d_in[0];
    const float* w   = (const float*)d_in[1];
    const int*   idx = (const int*)d_in[2];
    float* out = (float*)d_out;
    int*   ws  = (int*)d_ws;

    SwitchLinear_setup_kernel<<<1, 256, 0, stream>>>(idx, ws);
    SwitchLinear_gemm_kernel<<<GRID, 512, 0, stream>>>(x, w, ws, out);
}

// Round 3
// 616.536 us; speedup vs baseline: 2.2738x; 2.2738x over previous
//
#include <hip/hip_runtime.h>
#include <hip/hip_bf16.h>
#include <stdint.h>

#define N_TOK 8192
#define D_IN  2048
#define D_OUT 8192
#define NEXP  8
#define NT_MAX 72            /* max 128-row tiles (<= 64+7 worst case) */
#define KSTEPS 32            /* D_IN / 64 */
#define NSTRIPS 64           /* D_OUT / 128 */
#define IMG_B  16384         /* one 128x64 bf16 swizzled LDS image */
#define X_OFF  65536
#define X_BYTES (NT_MAX * KSTEPS * IMG_B)
#define W_OFF  (X_OFF + X_BYTES)
#define W_BYTES ((long)NEXP * NSTRIPS * KSTEPS * IMG_B)
#define WS_NEED ((size_t)W_OFF + (size_t)W_BYTES)

// ws meta (int units): [0] nt; [8..80) expert; [96..168) row_start;
// [192..264) rows; [512..512+N) order

typedef float  f32x4  __attribute__((ext_vector_type(4)));
typedef __bf16 bf16x8 __attribute__((ext_vector_type(8)));

__global__ void SwitchLinear_setup_kernel(const int* __restrict__ idx,
                                          int* __restrict__ ws) {
    __shared__ int cnt[NEXP], cur[NEXP];
    int t = threadIdx.x;
    if (t < NEXP) cnt[t] = 0;
    __syncthreads();
    for (int i = t; i < N_TOK; i += 256) atomicAdd(&cnt[idx[i]], 1);
    __syncthreads();
    if (t == 0) {
        int o = 0, nt = 0;
        for (int e = 0; e < NEXP; ++e) {
            cur[e] = o;
            int c = cnt[e];
            for (int r = 0; r < c; r += 128) {
                ws[8 + nt]   = e;
                ws[96 + nt]  = o + r;
                ws[192 + nt] = (c - r < 128) ? (c - r) : 128;
                ++nt;
            }
            o += c;
        }
        ws[0] = nt;
    }
    __syncthreads();
    for (int i = t; i < N_TOK; i += 256) {
        int p = atomicAdd(&cur[idx[i]], 1);
        ws[512 + p] = i;
    }
}

// ---------------- fast path: pre-convert to swizzled bf16 images ----------

// image layout: row r (0..127) of 128 bytes; 16-B chunk c stored at
// byte r*128 + ((c ^ (r&7))<<4). Fragment reads are then ~2-way (free).

__global__ __launch_bounds__(256) void SwitchLinear_convx_kernel(
    const float* __restrict__ x, const int* __restrict__ ws,
    char* __restrict__ wsb) {
    const int tile = blockIdx.x, kst = blockIdx.y;
    if (tile >= ws[0]) return;
    const int rs = ws[96 + tile], rows = ws[192 + tile];
    char* img = wsb + X_OFF + (long)(tile * KSTEPS + kst) * IMG_B;
    const int t = threadIdx.x;
#pragma unroll
    for (int i = 0; i < 4; ++i) {
        int u = t + i * 256;
        int r = u >> 3, kc = u & 7;
        int rl = rs + (r < rows ? r : rows - 1);
        int token = ws[512 + rl];
        const float* src = x + (long)token * D_IN + kst * 64 + kc * 8;
        f32x4 v0 = *(const f32x4*)src;
        f32x4 v1 = *(const f32x4*)(src + 4);
        union { __bf16 h[8]; uint4 u4; } c;
        c.h[0] = (__bf16)v0[0]; c.h[1] = (__bf16)v0[1];
        c.h[2] = (__bf16)v0[2]; c.h[3] = (__bf16)v0[3];
        c.h[4] = (__bf16)v1[0]; c.h[5] = (__bf16)v1[1];
        c.h[6] = (__bf16)v1[2]; c.h[7] = (__bf16)v1[3];
        *(uint4*)(img + r * 128 + ((kc ^ (r & 7)) << 4)) = c.u4;
    }
}

__global__ __launch_bounds__(256) void SwitchLinear_convw_kernel(
    const float* __restrict__ w, char* __restrict__ wsb) {
    const int img = blockIdx.x;
    const int kst = img & 31, strip = (img >> 5) & 63, e = img >> 11;
    __shared__ float tl[64 * 129];
    const float* src = w + (long)e * D_IN * D_OUT + (long)(kst * 64) * D_OUT + strip * 128;
    const int t = threadIdx.x;
#pragma unroll
    for (int i = 0; i < 8; ++i) {
        int u = t + i * 256;
        int row = u >> 5, ch = u & 31;
        f32x4 v = *(const f32x4*)(src + (long)row * D_OUT + ch * 4);
        float* d = &tl[row * 129 + ch * 4];
        d[0] = v[0]; d[1] = v[1]; d[2] = v[2]; d[3] = v[3];
    }
    __syncthreads();
    char* dimg = wsb + W_OFF + (long)img * IMG_B;
#pragma unroll
    for (int i = 0; i < 4; ++i) {
        int u = t + i * 256;
        int n = u >> 3, kc = u & 7;
        union { __bf16 h[8]; uint4 u4; } c;
#pragma unroll
        for (int j = 0; j < 8; ++j) c.h[j] = (__bf16)tl[(kc * 8 + j) * 129 + n];
        *(uint4*)(dimg + n * 128 + ((kc ^ (n & 7)) << 4)) = c.u4;
    }
}

__global__ __launch_bounds__(256, 3) void SwitchLinear_gemm_kernel(
    const char* __restrict__ wsb, const int* __restrict__ ws,
    float* __restrict__ out) {
    // strip-major logical order, XCD-chunked bijective swizzle (4608 = 8*576)
    const int bid = blockIdx.x;
    const int lb  = (bid & 7) * (NT_MAX * NSTRIPS / 8) + (bid >> 3);
    const int tx  = lb % NT_MAX;
    const int y   = lb / NT_MAX;
    if (tx >= ws[0]) return;
    const int e = ws[8 + tx], rs = ws[96 + tx], rows = ws[192 + tx];

    __shared__ __align__(16) unsigned short As[128 * 64];
    __shared__ __align__(16) unsigned short Bs[128 * 64];
    __shared__ int ord[128];

    const int t = threadIdx.x;
    if (t < 128) {
        int r = (t < rows) ? (rs + t) : rs;
        ord[t] = ws[512 + r];
    }

    const char* aBase = wsb + X_OFF + (long)(tx * KSTEPS) * IMG_B;
    const char* bBase = wsb + W_OFF + (long)((e * NSTRIPS + y) * KSTEPS) * IMG_B;

    const int lane = t & 63;
    const int wid  = t >> 6;
    const int wr = wid >> 1, wc = wid & 1;     // 2x2 wave grid, 64x64 per wave
    const int lm = lane & 15, lk = lane >> 4;

    f32x4 acc[4][4];
#pragma unroll
    for (int i = 0; i < 4; ++i)
#pragma unroll
        for (int j = 0; j < 4; ++j) acc[i][j] = (f32x4){0.f, 0.f, 0.f, 0.f};

    for (int kt = 0; kt < KSTEPS; ++kt) {
        const char* aImg = aBase + kt * IMG_B;
        const char* bImg = bBase + kt * IMG_B;
#pragma unroll
        for (int i = 0; i < 4; ++i) {
            const int off = i * 4096 + t * 16;
            __builtin_amdgcn_global_load_lds(
                (const __attribute__((address_space(1))) uint32_t*)(aImg + off),
                (__attribute__((address_space(3))) uint32_t*)((char*)As + off),
                16, 0, 0);
            __builtin_amdgcn_global_load_lds(
                (const __attribute__((address_space(1))) uint32_t*)(bImg + off),
                (__attribute__((address_space(3))) uint32_t*)((char*)Bs + off),
                16, 0, 0);
        }
        __syncthreads();
#pragma unroll
        for (int ks = 0; ks < 2; ++ks) {
            const int cbase = ks * 4 + lk;     // 16-B chunk index 0..7
            bf16x8 a[4], b[4];
#pragma unroll
            for (int mi = 0; mi < 4; ++mi) {
                int r = wr * 64 + mi * 16 + lm;
                a[mi] = *(const bf16x8*)((const char*)As + r * 128 + ((cbase ^ (r & 7)) << 4));
            }
#pragma unroll
            for (int ni = 0; ni < 4; ++ni) {
                int n = wc * 64 + ni * 16 + lm;
                b[ni] = *(const bf16x8*)((const char*)Bs + n * 128 + ((cbase ^ (n & 7)) << 4));
            }
#pragma unroll
            for (int mi = 0; mi < 4; ++mi)
#pragma unroll
                for (int ni = 0; ni < 4; ++ni)
                    acc[mi][ni] = __builtin_amdgcn_mfma_f32_16x16x32_bf16(
                        a[mi], b[ni], acc[mi][ni], 0, 0, 0);
        }
        __syncthreads();
    }

    // epilogue: C/D layout col=lane&15, row=(lane>>4)*4+reg
#pragma unroll
    for (int mi = 0; mi < 4; ++mi) {
#pragma unroll
        for (int j = 0; j < 4; ++j) {
            int rl = wr * 64 + mi * 16 + lk * 4 + j;
            if (rl < rows) {
                int token = ord[rl];
                float* po = out + (long)token * D_OUT + y * 128 + wc * 64 + lm;
#pragma unroll
                for (int ni = 0; ni < 4; ++ni) po[ni * 16] = acc[mi][ni][j];
            }
        }
    }
}

// ---------------- fallback path (round-1 kernel, known-good) --------------

__device__ __forceinline__ int fb_a_byte(int r, int kbyte) {
    return r * 128 + (kbyte ^ ((r & 7) << 4));
}
__device__ __forceinline__ int fb_b_byte(int n, int kbyte) {
    int slot = (n ^ (n >> 2)) & 7;
    return n * 128 + (kbyte ^ (slot << 4));
}

__global__ __launch_bounds__(256, 2) void SwitchLinear_gemm_fb_kernel(
    const float* __restrict__ x, const float* __restrict__ w,
    const int* __restrict__ ws, float* __restrict__ out) {
    const int nt = ws[0];
    const int tx = blockIdx.x;
    if (tx >= nt) return;
    const int e    = ws[8 + tx];
    const int rs   = ws[96 + tx];
    const int rows = ws[192 + tx];
    const int col0 = blockIdx.y * 128;

    __shared__ __align__(16) unsigned short As[128 * 64];
    __shared__ __align__(16) unsigned short Bs[128 * 64];
    __shared__ int ord[128];

    const int t = threadIdx.x;
    if (t < 128) {
        int r = (t < rows) ? (rs + t) : rs;
        ord[t] = ws[512 + r];
    }
    __syncthreads();

    const int kq = t & 15;
    const float* pA[8];
    int rowA[8];
#pragma unroll
    for (int i = 0; i < 8; ++i) {
        int r = (t >> 4) + 16 * i;
        rowA[i] = r;
        pA[i] = x + (long)ord[r] * D_IN + kq * 4;
    }
    const float* pB[2];
    int nB[2], kbB[2];
#pragma unroll
    for (int i = 0; i < 2; ++i) {
        int u = t + 256 * i;
        int kg = u >> 5, q = u & 31;
        kbB[i] = kg * 4;
        nB[i]  = q * 4;
        pB[i]  = w + (long)e * D_IN * D_OUT + (long)(kg * 4) * D_OUT + col0 + q * 4;
    }

    const int lane = t & 63;
    const int wid  = t >> 6;
    const int wr = wid >> 1, wc = wid & 1;
    const int lm = lane & 15, lk = lane >> 4;

    f32x4 acc[4][4];
#pragma unroll
    for (int i = 0; i < 4; ++i)
#pragma unroll
        for (int j = 0; j < 4; ++j) acc[i][j] = (f32x4){0.f, 0.f, 0.f, 0.f};

    for (int k0 = 0; k0 < D_IN; k0 += 64) {
#pragma unroll
        for (int i = 0; i < 8; ++i) {
            f32x4 v = *(const f32x4*)(pA[i] + k0);
            union { __bf16 h[4]; uint2 u; } c;
            c.h[0] = (__bf16)v[0]; c.h[1] = (__bf16)v[1];
            c.h[2] = (__bf16)v[2]; c.h[3] = (__bf16)v[3];
            *(uint2*)((char*)As + fb_a_byte(rowA[i], kq * 8)) = c.u;
        }
#pragma unroll
        for (int i = 0; i < 2; ++i) {
            const float* p = pB[i] + (long)k0 * D_OUT;
            f32x4 r0 = *(const f32x4*)(p);
            f32x4 r1 = *(const f32x4*)(p + D_OUT);
            f32x4 r2 = *(const f32x4*)(p + 2 * D_OUT);
            f32x4 r3 = *(const f32x4*)(p + 3 * D_OUT);
#pragma unroll
            for (int j = 0; j < 4; ++j) {
                int n = nB[i] + j;
                union { __bf16 h[4]; uint2 u; } c;
                c.h[0] = (__bf16)r0[j]; c.h[1] = (__bf16)r1[j];
                c.h[2] = (__bf16)r2[j]; c.h[3] = (__bf16)r3[j];
                *(uint2*)((char*)Bs + fb_b_byte(n, kbB[i] * 2)) = c.u;
            }
        }
        __syncthreads();
#pragma unroll
        for (int ks = 0; ks < 2; ++ks) {
            bf16x8 a[4], b[4];
            const int kbyte = ks * 64 + lk * 16;
#pragma unroll
            for (int mi = 0; mi < 4; ++mi) {
                int r = wr * 64 + mi * 16 + lm;
                a[mi] = *(const bf16x8*)((const char*)As + fb_a_byte(r, kbyte));
            }
#pragma unroll
            for (int ni = 0; ni < 4; ++ni) {
                int n = wc * 64 + ni * 16 + lm;
                b[ni] = *(const bf16x8*)((const char*)Bs + fb_b_byte(n, kbyte));
            }
#pragma unroll
            for (int mi = 0; mi < 4; ++mi)
#pragma unroll
                for (int ni = 0; ni < 4; ++ni)
                    acc[mi][ni] = __builtin_amdgcn_mfma_f32_16x16x32_bf16(
                        a[mi], b[ni], acc[mi][ni], 0, 0, 0);
        }
        __syncthreads();
    }
#pragma unroll
    for (int mi = 0; mi < 4; ++mi) {
#pragma unroll
        for (int j = 0; j < 4; ++j) {
            int rl = wr * 64 + mi * 16 + lk * 4 + j;
            if (rl < rows) {
                int token = ord[rl];
                float* po = out + (long)token * D_OUT + col0 + wc * 64 + lm;
#pragma unroll
                for (int ni = 0; ni < 4; ++ni) po[ni * 16] = acc[mi][ni][j];
            }
        }
    }
}

extern "C" void kernel_launch(void* const* d_in, const int* in_sizes, int n_in,
                              void* d_out, int out_size, void* d_ws, size_t ws_size,
                              hipStream_t stream) {
    const float* x   = (const float*)d_in[0];
    const float* w   = (const float*)d_in[1];
    const int*   idx = (const int*)d_in[2];
    float* out = (float*)d_out;
    int*   ws  = (int*)d_ws;
    char*  wsb = (char*)d_ws;

    SwitchLinear_setup_kernel<<<1, 256, 0, stream>>>(idx, ws);
    if (ws_size >= WS_NEED) {
        SwitchLinear_convx_kernel<<<dim3(NT_MAX, KSTEPS), 256, 0, stream>>>(x, ws, wsb);
        SwitchLinear_convw_kernel<<<NEXP * NSTRIPS * KSTEPS, 256, 0, stream>>>(w, wsb);
        SwitchLinear_gemm_kernel<<<NT_MAX * NSTRIPS, 256, 0, stream>>>(wsb, ws, out);
    } else {
        dim3 grid(NT_MAX, NSTRIPS);
        SwitchLinear_gemm_fb_kernel<<<grid, 256, 0, stream>>>(x, w, ws, out);
    }
}

// Round 4
// 597.848 us; speedup vs baseline: 2.3448x; 1.0313x over previous
//
#include <hip/hip_runtime.h>
#include <hip/hip_bf16.h>
#include <stdint.h>

#define N_TOK 8192
#define D_IN  2048
#define D_OUT 8192
#define NEXP  8
#define KST   32                /* D_IN / 64 */
#define NT2   40                /* max 256-row tiles (32 + 7 = 39) */
#define NS2   32                /* 256-col strips */
#define AIMG  32768             /* one (tile|strip, kstep) image: [h][ks][128][64B] */
#define X_OFF2 65536
#define X_BYTES2 ((long)NT2 * KST * AIMG)                /* 40 MB  */
#define W_OFF2 (X_OFF2 + X_BYTES2)
#define W_BYTES2 ((long)NEXP * NS2 * KST * AIMG)         /* 256 MB */
#define WS_NEED2 ((size_t)(W_OFF2 + W_BYTES2))

// ws meta (int units): [0] nt256; [8..48) expert; [96..136) row_start;
// [192..232) rows; fb 128-tiles: [256..328) e, [328..400) rs, [400..472) rows;
// [4] nt128; [512..512+N) order

typedef float  f32x4  __attribute__((ext_vector_type(4)));
typedef __bf16 bf16x8 __attribute__((ext_vector_type(8)));

__global__ void SwitchLinear_setup_kernel(const int* __restrict__ idx,
                                          int* __restrict__ ws) {
    __shared__ int cnt[NEXP], cur[NEXP];
    int t = threadIdx.x;
    if (t < NEXP) cnt[t] = 0;
    __syncthreads();
    for (int i = t; i < N_TOK; i += 256) atomicAdd(&cnt[idx[i]], 1);
    __syncthreads();
    if (t == 0) {
        int o = 0, nt = 0, nt1 = 0;
        for (int e = 0; e < NEXP; ++e) {
            cur[e] = o;
            int c = cnt[e];
            for (int r = 0; r < c; r += 256) {
                ws[8 + nt]   = e;
                ws[96 + nt]  = o + r;
                ws[192 + nt] = (c - r < 256) ? (c - r) : 256;
                ++nt;
            }
            for (int r = 0; r < c; r += 128) {
                ws[256 + nt1] = e;
                ws[328 + nt1] = o + r;
                ws[400 + nt1] = (c - r < 128) ? (c - r) : 128;
                ++nt1;
            }
            o += c;
        }
        ws[0] = nt;
        ws[4] = nt1;
    }
    __syncthreads();
    for (int i = t; i < N_TOK; i += 256) {
        int p = atomicAdd(&cur[idx[i]], 1);
        ws[512 + p] = i;
    }
}

// ---------- conversion to pre-swizzled bf16 images ------------------------
// image: [h][ks][128 rows][64B]; element (r, k): ks=k>>5, c=(k>>3)&3, j=k&7
// byte = h*16384 + ks*8192 + r*64 + ((c ^ (r&3))<<4) + j*2

__global__ __launch_bounds__(256) void SwitchLinear_convx_kernel(
    const float* __restrict__ x, const int* __restrict__ ws,
    char* __restrict__ wsb) {
    const int tile = blockIdx.x, kst = blockIdx.y;
    if (tile >= ws[0]) return;
    const int rs = ws[96 + tile], rows = ws[192 + tile];
    char* img = wsb + X_OFF2 + (long)(tile * KST + kst) * AIMG;
    const int t = threadIdx.x;
#pragma unroll
    for (int i = 0; i < 8; ++i) {
        int u = t + i * 256;            // 0..2047
        int h = u >> 10, rem = u & 1023;
        int r = rem >> 3, kc8 = rem & 7;
        int R = h * 128 + r;
        int rl = rs + (R < rows ? R : rows - 1);
        int token = ws[512 + rl];
        const float* src = x + (long)token * D_IN + kst * 64 + kc8 * 8;
        f32x4 v0 = *(const f32x4*)src;
        f32x4 v1 = *(const f32x4*)(src + 4);
        union { __bf16 hh[8]; uint4 u4; } c;
        c.hh[0] = (__bf16)v0[0]; c.hh[1] = (__bf16)v0[1];
        c.hh[2] = (__bf16)v0[2]; c.hh[3] = (__bf16)v0[3];
        c.hh[4] = (__bf16)v1[0]; c.hh[5] = (__bf16)v1[1];
        c.hh[6] = (__bf16)v1[2]; c.hh[7] = (__bf16)v1[3];
        *(uint4*)(img + h * 16384 + (kc8 >> 2) * 8192 + r * 64 +
                  (((kc8 & 3) ^ (r & 3)) << 4)) = c.u4;
    }
}

__global__ __launch_bounds__(256) void SwitchLinear_convw_kernel(
    const float* __restrict__ w, char* __restrict__ wsb) {
    const int img = blockIdx.x;          // (e, strip128 s, kst)
    const int kst = img & 31, s = (img >> 5) & 63, e = img >> 11;
    const int y = s >> 1, h = s & 1;
    __shared__ float tl[64 * 129];
    const float* src = w + (long)e * D_IN * D_OUT + (long)(kst * 64) * D_OUT +
                       y * 256 + h * 128;
    const int t = threadIdx.x;
#pragma unroll
    for (int i = 0; i < 8; ++i) {
        int u = t + i * 256;
        int row = u >> 5, ch = u & 31;   // 64 k-rows x 128 cols
        f32x4 v = *(const f32x4*)(src + (long)row * D_OUT + ch * 4);
        float* d = &tl[row * 129 + ch * 4];
        d[0] = v[0]; d[1] = v[1]; d[2] = v[2]; d[3] = v[3];
    }
    __syncthreads();
    char* dimg = wsb + W_OFF2 + (long)((e * NS2 + y) * KST + kst) * AIMG + h * 16384;
#pragma unroll
    for (int i = 0; i < 4; ++i) {
        int u = t + i * 256;             // 0..1023
        int cc = u >> 3, kc8 = u & 7;
        union { __bf16 hh[8]; uint4 u4; } c;
#pragma unroll
        for (int j = 0; j < 8; ++j) c.hh[j] = (__bf16)tl[(kc8 * 8 + j) * 129 + cc];
        *(uint4*)(dimg + (kc8 >> 2) * 8192 + cc * 64 +
                  (((kc8 & 3) ^ (cc & 3)) << 4)) = c.u4;
    }
}

// ---------- 256x256 8-phase GEMM ------------------------------------------

__global__ __launch_bounds__(512, 1) void SwitchLinear_gemm_kernel(
    const char* __restrict__ wsb, const int* __restrict__ ws,
    float* __restrict__ out) {
    const int bid = blockIdx.x;
    const int lb  = (bid & 7) * ((NT2 * NS2) / 8) + (bid >> 3);
    const int tx  = lb % NT2;
    const int y   = lb / NT2;
    if (tx >= ws[0]) return;
    const int e = ws[8 + tx], rs = ws[96 + tx], rows = ws[192 + tx];

    __shared__ __align__(16) char lds[2][2][2][2][8192]; // [buf][A/B][h][ks]
    __shared__ int ord[256];

    const int t = threadIdx.x;
    if (t < 256) ord[t] = ws[512 + rs + (t < rows ? t : 0)];
    __syncthreads();

    const char* aImg = wsb + X_OFF2 + (long)(tx * KST) * AIMG;
    const char* bImg = wsb + W_OFF2 + (long)((e * NS2 + y) * KST) * AIMG;

    const int lane = t & 63;
    const int wid  = t >> 6;
    const int wr = wid >> 2, wc = wid & 3;   // 2(M) x 4(N) waves; 128x64 each
    const int lm = lane & 15, lk = lane >> 4;

    f32x4 acc[8][4];
#pragma unroll
    for (int i = 0; i < 8; ++i)
#pragma unroll
        for (int j = 0; j < 4; ++j) acc[i][j] = (f32x4){0.f, 0.f, 0.f, 0.f};

    bf16x8 aa[4], bb[4];

#define STG(op, h, ks, tt)                                                    \
    __builtin_amdgcn_global_load_lds(                                         \
        (const __attribute__((address_space(1))) uint32_t*)(                  \
            ((op) ? bImg : aImg) + (long)(tt) * AIMG + (h) * 16384 +          \
            (ks) * 8192 + t * 16),                                            \
        (__attribute__((address_space(3))) uint32_t*)(                        \
            &lds[(tt) & 1][op][h][ks][t * 16]),                               \
        16, 0, 0)

#define LDB(p, ks)                                                            \
    do { _Pragma("unroll")                                                    \
        for (int ni = 0; ni < 4; ++ni) {                                      \
            int cc = (wc & 1) * 64 + ni * 16 + lm;                            \
            bb[ni] = *(const bf16x8*)(&lds[p][1][wc >> 1][ks]                 \
                         [cc * 64 + ((lk ^ (cc & 3)) << 4)]);                 \
        } } while (0)

#define LDA(p, ks, mh)                                                        \
    do { _Pragma("unroll")                                                    \
        for (int q = 0; q < 4; ++q) {                                         \
            int rr = (mh) * 64 + q * 16 + lm;                                 \
            aa[q] = *(const bf16x8*)(&lds[p][0][wr][ks]                       \
                         [rr * 64 + ((lk ^ (rr & 3)) << 4)]);                 \
        } } while (0)

#define MFMA16(mh)                                                            \
    do { _Pragma("unroll")                                                    \
        for (int q = 0; q < 4; ++q)                                           \
            _Pragma("unroll")                                                 \
            for (int ni = 0; ni < 4; ++ni)                                    \
                acc[(mh) * 4 + q][ni] = __builtin_amdgcn_mfma_f32_16x16x32_bf16( \
                    aa[q], bb[ni], acc[(mh) * 4 + q][ni], 0, 0, 0);           \
    } while (0)

#define PH(p, ks, mh, DOB, ISSUE, WAITASM)                                    \
    do {                                                                      \
        if (DOB) LDB(p, ks);                                                  \
        LDA(p, ks, mh);                                                       \
        ISSUE;                                                                \
        WAITASM;                                                              \
        __builtin_amdgcn_s_barrier();                                         \
        asm volatile("s_waitcnt lgkmcnt(0)" ::: "memory");                    \
        __builtin_amdgcn_sched_barrier(0);                                    \
        __builtin_amdgcn_s_setprio(1);                                        \
        MFMA16(mh);                                                           \
        __builtin_amdgcn_s_setprio(0);                                        \
        __builtin_amdgcn_s_barrier();                                         \
    } while (0)

    // prologue: stage tile 0 (k0 halves first, then k1)
    STG(0, 0, 0, 0); STG(0, 1, 0, 0); STG(1, 0, 0, 0); STG(1, 1, 0, 0);
    STG(0, 0, 1, 0); STG(0, 1, 1, 0); STG(1, 0, 1, 0); STG(1, 1, 1, 0);
    asm volatile("s_waitcnt vmcnt(4)" ::: "memory");   // tile0 k0 resident
    __builtin_amdgcn_s_barrier();

    for (int tt = 0; tt < KST - 1; ++tt) {
        const int p = tt & 1;
        const int nx = tt + 1;
        PH(p, 0, 0, 1, { STG(0, 0, 0, nx); STG(0, 1, 0, nx); }, ((void)0));
        PH(p, 0, 1, 0, { STG(1, 0, 0, nx); STG(1, 1, 0, nx); },
           asm volatile("s_waitcnt vmcnt(4)" ::: "memory"));
        PH(p, 1, 0, 1, { STG(0, 0, 1, nx); STG(0, 1, 1, nx); }, ((void)0));
        PH(p, 1, 1, 0, { STG(1, 0, 1, nx); STG(1, 1, 1, nx); },
           asm volatile("s_waitcnt vmcnt(4)" ::: "memory"));
    }
    {   // peeled last tile (KST-1): no issues; drain k1 before ks=1 phases
        const int p = (KST - 1) & 1;
        PH(p, 0, 0, 1, ((void)0), ((void)0));
        PH(p, 0, 1, 0, ((void)0),
           asm volatile("s_waitcnt vmcnt(0)" ::: "memory"));
        PH(p, 1, 0, 1, ((void)0), ((void)0));
        PH(p, 1, 1, 0, ((void)0), ((void)0));
    }

    // epilogue: C/D layout col=lane&15, row=(lane>>4)*4+reg
#pragma unroll
    for (int mi = 0; mi < 8; ++mi) {
#pragma unroll
        for (int j = 0; j < 4; ++j) {
            int rl = wr * 128 + mi * 16 + lk * 4 + j;
            if (rl < rows) {
                int token = ord[rl];
                float* po = out + (long)token * D_OUT + y * 256 + wc * 64 + lm;
#pragma unroll
                for (int ni = 0; ni < 4; ++ni) po[ni * 16] = acc[mi][ni][j];
            }
        }
    }
#undef STG
#undef LDB
#undef LDA
#undef MFMA16
#undef PH
}

// ---------- fallback (direct fp32, known-good round-1 structure) ----------

__device__ __forceinline__ int fb_a_byte(int r, int kbyte) {
    return r * 128 + (kbyte ^ ((r & 7) << 4));
}
__device__ __forceinline__ int fb_b_byte(int n, int kbyte) {
    int slot = (n ^ (n >> 2)) & 7;
    return n * 128 + (kbyte ^ (slot << 4));
}

__global__ __launch_bounds__(256, 2) void SwitchLinear_gemm_fb_kernel(
    const float* __restrict__ x, const float* __restrict__ w,
    const int* __restrict__ ws, float* __restrict__ out) {
    const int nt = ws[4];
    const int tx = blockIdx.x;
    if (tx >= nt) return;
    const int e    = ws[256 + tx];
    const int rs   = ws[328 + tx];
    const int rows = ws[400 + tx];
    const int col0 = blockIdx.y * 128;

    __shared__ __align__(16) unsigned short As[128 * 64];
    __shared__ __align__(16) unsigned short Bs[128 * 64];
    __shared__ int ord[128];

    const int t = threadIdx.x;
    if (t < 128) {
        int r = (t < rows) ? (rs + t) : rs;
        ord[t] = ws[512 + r];
    }
    __syncthreads();

    const int kq = t & 15;
    const float* pA[8];
    int rowA[8];
#pragma unroll
    for (int i = 0; i < 8; ++i) {
        int r = (t >> 4) + 16 * i;
        rowA[i] = r;
        pA[i] = x + (long)ord[r] * D_IN + kq * 4;
    }
    const float* pB[2];
    int nB[2], kbB[2];
#pragma unroll
    for (int i = 0; i < 2; ++i) {
        int u = t + 256 * i;
        int kg = u >> 5, q = u & 31;
        kbB[i] = kg * 4;
        nB[i]  = q * 4;
        pB[i]  = w + (long)e * D_IN * D_OUT + (long)(kg * 4) * D_OUT + col0 + q * 4;
    }

    const int lane = t & 63;
    const int wid  = t >> 6;
    const int wr = wid >> 1, wc = wid & 1;
    const int lm = lane & 15, lk = lane >> 4;

    f32x4 acc[4][4];
#pragma unroll
    for (int i = 0; i < 4; ++i)
#pragma unroll
        for (int j = 0; j < 4; ++j) acc[i][j] = (f32x4){0.f, 0.f, 0.f, 0.f};

    for (int k0 = 0; k0 < D_IN; k0 += 64) {
#pragma unroll
        for (int i = 0; i < 8; ++i) {
            f32x4 v = *(const f32x4*)(pA[i] + k0);
            union { __bf16 h[4]; uint2 u; } c;
            c.h[0] = (__bf16)v[0]; c.h[1] = (__bf16)v[1];
            c.h[2] = (__bf16)v[2]; c.h[3] = (__bf16)v[3];
            *(uint2*)((char*)As + fb_a_byte(rowA[i], kq * 8)) = c.u;
        }
#pragma unroll
        for (int i = 0; i < 2; ++i) {
            const float* p = pB[i] + (long)k0 * D_OUT;
            f32x4 r0 = *(const f32x4*)(p);
            f32x4 r1 = *(const f32x4*)(p + D_OUT);
            f32x4 r2 = *(const f32x4*)(p + 2 * D_OUT);
            f32x4 r3 = *(const f32x4*)(p + 3 * D_OUT);
#pragma unroll
            for (int j = 0; j < 4; ++j) {
                int n = nB[i] + j;
                union { __bf16 h[4]; uint2 u; } c;
                c.h[0] = (__bf16)r0[j]; c.h[1] = (__bf16)r1[j];
                c.h[2] = (__bf16)r2[j]; c.h[3] = (__bf16)r3[j];
                *(uint2*)((char*)Bs + fb_b_byte(n, kbB[i] * 2)) = c.u;
            }
        }
        __syncthreads();
#pragma unroll
        for (int ks = 0; ks < 2; ++ks) {
            bf16x8 a[4], b[4];
            const int kbyte = ks * 64 + lk * 16;
#pragma unroll
            for (int mi = 0; mi < 4; ++mi) {
                int r = wr * 64 + mi * 16 + lm;
                a[mi] = *(const bf16x8*)((const char*)As + fb_a_byte(r, kbyte));
            }
#pragma unroll
            for (int ni = 0; ni < 4; ++ni) {
                int n = wc * 64 + ni * 16 + lm;
                b[ni] = *(const bf16x8*)((const char*)Bs + fb_b_byte(n, kbyte));
            }
#pragma unroll
            for (int mi = 0; mi < 4; ++mi)
#pragma unroll
                for (int ni = 0; ni < 4; ++ni)
                    acc[mi][ni] = __builtin_amdgcn_mfma_f32_16x16x32_bf16(
                        a[mi], b[ni], acc[mi][ni], 0, 0, 0);
        }
        __syncthreads();
    }
#pragma unroll
    for (int mi = 0; mi < 4; ++mi) {
#pragma unroll
        for (int j = 0; j < 4; ++j) {
            int rl = wr * 64 + mi * 16 + lk * 4 + j;
            if (rl < rows) {
                int token = ord[rl];
                float* po = out + (long)token * D_OUT + col0 + wc * 64 + lm;
#pragma unroll
                for (int ni = 0; ni < 4; ++ni) po[ni * 16] = acc[mi][ni][j];
            }
        }
    }
}

extern "C" void kernel_launch(void* const* d_in, const int* in_sizes, int n_in,
                              void* d_out, int out_size, void* d_ws, size_t ws_size,
                              hipStream_t stream) {
    const float* x   = (const float*)d_in[0];
    const float* w   = (const float*)d_in[1];
    const int*   idx = (const int*)d_in[2];
    float* out = (float*)d_out;
    int*   ws  = (int*)d_ws;
    char*  wsb = (char*)d_ws;

    SwitchLinear_setup_kernel<<<1, 256, 0, stream>>>(idx, ws);
    if (ws_size >= WS_NEED2) {
        SwitchLinear_convx_kernel<<<dim3(NT2, KST), 256, 0, stream>>>(x, ws, wsb);
        SwitchLinear_convw_kernel<<<NEXP * 64 * KST, 256, 0, stream>>>(w, wsb);
        SwitchLinear_gemm_kernel<<<NT2 * NS2, 512, 0, stream>>>(wsb, ws, out);
    } else {
        dim3 grid(72, 64);
        SwitchLinear_gemm_fb_kernel<<<grid, 256, 0, stream>>>(x, w, ws, out);
    }
}

// Round 5
// 565.279 us; speedup vs baseline: 2.4799x; 1.0576x over previous
//
#include <hip/hip_runtime.h>
#include <hip/hip_bf16.h>
#include <stdint.h>

#define N_TOK 8192
#define D_IN  2048
#define D_OUT 8192
#define NEXP  8
#define KST   32                /* D_IN / 64 */
#define NT2   40                /* max 256-row tiles */
#define NS2   32                /* 256-col strips */
#define AIMG  32768             /* one (tile|strip, kstep) image: [ks][pair-swizzled 16KB] */
#define X_OFF2 65536
#define X_BYTES2 ((long)NT2 * KST * AIMG)                /* 40 MB  */
#define W_OFF2 (X_OFF2 + X_BYTES2)
#define W_BYTES2 ((long)NEXP * NS2 * KST * AIMG)         /* 256 MB */
#define WS_NEED2 ((size_t)(W_OFF2 + W_BYTES2))

// pair-row swizzle: element (r 0..255, chunk c 0..3 [16B=8 k-elems], ks)
// byte = ks*16384 + (r>>1)*128 + ((((r&1)<<2)|c) ^ ((r>>1)&7))*16
// read group (16 lanes, r=C..C+15, fixed c): slots hit 8 values x2 -> 2-way = free

typedef float  f32x4  __attribute__((ext_vector_type(4)));
typedef __bf16 bf16x8 __attribute__((ext_vector_type(8)));

__global__ void SwitchLinear_setup_kernel(const int* __restrict__ idx,
                                          int* __restrict__ ws) {
    __shared__ int cnt[NEXP], cur[NEXP];
    int t = threadIdx.x;
    if (t < NEXP) cnt[t] = 0;
    __syncthreads();
    for (int i = t; i < N_TOK; i += 256) atomicAdd(&cnt[idx[i]], 1);
    __syncthreads();
    if (t == 0) {
        int o = 0, nt = 0, nt1 = 0;
        for (int e = 0; e < NEXP; ++e) {
            cur[e] = o;
            int c = cnt[e];
            for (int r = 0; r < c; r += 256) {
                ws[8 + nt]   = e;
                ws[96 + nt]  = o + r;
                ws[192 + nt] = (c - r < 256) ? (c - r) : 256;
                ++nt;
            }
            for (int r = 0; r < c; r += 128) {
                ws[256 + nt1] = e;
                ws[328 + nt1] = o + r;
                ws[400 + nt1] = (c - r < 128) ? (c - r) : 128;
                ++nt1;
            }
            o += c;
        }
        ws[0] = nt;
        ws[4] = nt1;
    }
    __syncthreads();
    for (int i = t; i < N_TOK; i += 256) {
        int p = atomicAdd(&cur[idx[i]], 1);
        ws[512 + p] = i;
    }
}

// ---------- conversion to pre-swizzled bf16 images ------------------------

__global__ __launch_bounds__(256) void SwitchLinear_convx_kernel(
    const float* __restrict__ x, const int* __restrict__ ws,
    char* __restrict__ wsb) {
    const int tile = blockIdx.x, kst = blockIdx.y;
    if (tile >= ws[0]) return;
    const int rs = ws[96 + tile], rows = ws[192 + tile];
    char* img = wsb + X_OFF2 + (long)(tile * KST + kst) * AIMG;
    const int t = threadIdx.x;
#pragma unroll
    for (int i = 0; i < 8; ++i) {
        int u = t + i * 256;            // 0..2047
        int R = u >> 3, kc8 = u & 7;    // R: 0..255, kc8: 8-elem k-chunk
        int rl = rs + (R < rows ? R : rows - 1);
        int token = ws[512 + rl];
        const float* src = x + (long)token * D_IN + kst * 64 + kc8 * 8;
        f32x4 v0 = *(const f32x4*)src;
        f32x4 v1 = *(const f32x4*)(src + 4);
        union { __bf16 hh[8]; uint4 u4; } c;
        c.hh[0] = (__bf16)v0[0]; c.hh[1] = (__bf16)v0[1];
        c.hh[2] = (__bf16)v0[2]; c.hh[3] = (__bf16)v0[3];
        c.hh[4] = (__bf16)v1[0]; c.hh[5] = (__bf16)v1[1];
        c.hh[6] = (__bf16)v1[2]; c.hh[7] = (__bf16)v1[3];
        int slot = (((R & 1) << 2) | (kc8 & 3)) ^ ((R >> 1) & 7);
        *(uint4*)(img + (kc8 >> 2) * 16384 + ((R >> 1) << 7) + (slot << 4)) = c.u4;
    }
}

__global__ __launch_bounds__(256) void SwitchLinear_convw_kernel(
    const float* __restrict__ w, char* __restrict__ wsb) {
    const int img = blockIdx.x;          // (e, strip128 s, kst)
    const int kst = img & 31, s = (img >> 5) & 63, e = img >> 11;
    const int y = s >> 1, hh = s & 1;
    __shared__ float tl[64 * 129];
    const float* src = w + (long)e * D_IN * D_OUT + (long)(kst * 64) * D_OUT +
                       y * 256 + hh * 128;
    const int t = threadIdx.x;
#pragma unroll
    for (int i = 0; i < 8; ++i) {
        int u = t + i * 256;
        int row = u >> 5, ch = u & 31;   // 64 k-rows x 128 cols (fp32)
        f32x4 v = *(const f32x4*)(src + (long)row * D_OUT + ch * 4);
        float* d = &tl[row * 129 + ch * 4];
        d[0] = v[0]; d[1] = v[1]; d[2] = v[2]; d[3] = v[3];
    }
    __syncthreads();
    char* dimg = wsb + W_OFF2 + (long)((e * NS2 + y) * KST + kst) * AIMG;
#pragma unroll
    for (int i = 0; i < 4; ++i) {
        int u = t + i * 256;             // 0..1023
        int cl = u >> 3, kc8 = u & 7;    // cl: local col 0..127
        union { __bf16 h8[8]; uint4 u4; } c;
#pragma unroll
        for (int j = 0; j < 8; ++j) c.h8[j] = (__bf16)tl[(kc8 * 8 + j) * 129 + cl];
        int cc = hh * 128 + cl;
        int slot = (((cc & 1) << 2) | (kc8 & 3)) ^ ((cc >> 1) & 7);
        *(uint4*)(dimg + (kc8 >> 2) * 16384 + ((cc >> 1) << 7) + (slot << 4)) = c.u4;
    }
}

// ---------- 256x256 8-phase GEMM ------------------------------------------

__global__ __launch_bounds__(512, 1) void SwitchLinear_gemm_kernel(
    const char* __restrict__ wsb, const int* __restrict__ ws,
    float* __restrict__ out) {
    const int bid = blockIdx.x;
    const int lb  = (bid & 7) * ((NT2 * NS2) / 8) + (bid >> 3);
    const int tx  = lb % NT2;
    const int y   = lb / NT2;
    if (tx >= ws[0]) return;
    const int e = ws[8 + tx], rs = ws[96 + tx], rows = ws[192 + tx];

    __shared__ __align__(16) char lds[2][2][2][16384]; // [buf][A=0/B=1][ks]
    __shared__ int ord[256];

    const int t = threadIdx.x;
    if (t < 256) ord[t] = ws[512 + rs + (t < rows ? t : 0)];
    __syncthreads();

    const char* aImg = wsb + X_OFF2 + (long)(tx * KST) * AIMG;
    const char* bImg = wsb + W_OFF2 + (long)((e * NS2 + y) * KST) * AIMG;

    const int lane = t & 63;
    const int wid  = t >> 6;
    const int wr = wid >> 2, wc = wid & 3;   // 2(M) x 4(N) waves; 128x64 each
    const int lm = lane & 15, lk = lane >> 4;

    f32x4 acc[8][4];
#pragma unroll
    for (int i = 0; i < 8; ++i)
#pragma unroll
        for (int j = 0; j < 4; ++j) acc[i][j] = (f32x4){0.f, 0.f, 0.f, 0.f};

    bf16x8 aa[4], bb[4];

#define STG(op, ks, half, tt)                                                 \
    __builtin_amdgcn_global_load_lds(                                         \
        (const __attribute__((address_space(1))) uint32_t*)(                  \
            ((op) ? bImg : aImg) + (long)(tt) * AIMG + (ks) * 16384 +         \
            (half) * 8192 + t * 16),                                          \
        (__attribute__((address_space(3))) uint32_t*)(                        \
            &lds[(tt) & 1][op][ks][(half) * 8192 + t * 16]),                  \
        16, 0, 0)

#define SWB(r) ((((r) >> 1) << 7) + (((((((r) & 1) << 2)) | lk) ^ (((r) >> 1) & 7)) << 4))

#define LDB(p, ks)                                                            \
    do { _Pragma("unroll")                                                    \
        for (int ni = 0; ni < 4; ++ni) {                                      \
            int cc = wc * 64 + ni * 16 + lm;                                  \
            bb[ni] = *(const bf16x8*)(&lds[p][1][ks][SWB(cc)]);               \
        } } while (0)

#define LDA(p, ks, mh)                                                        \
    do { _Pragma("unroll")                                                    \
        for (int q = 0; q < 4; ++q) {                                         \
            int rr = wr * 128 + (mh) * 64 + q * 16 + lm;                      \
            aa[q] = *(const bf16x8*)(&lds[p][0][ks][SWB(rr)]);                \
        } } while (0)

#define MFMA16(mh)                                                            \
    do { _Pragma("unroll")                                                    \
        for (int q = 0; q < 4; ++q)                                           \
            _Pragma("unroll")                                                 \
            for (int ni = 0; ni < 4; ++ni)                                    \
                acc[(mh) * 4 + q][ni] = __builtin_amdgcn_mfma_f32_16x16x32_bf16( \
                    aa[q], bb[ni], acc[(mh) * 4 + q][ni], 0, 0, 0);           \
    } while (0)

#define PH(p, ks, mh, DOB, ISSUE, WAITASM)                                    \
    do {                                                                      \
        if (DOB) LDB(p, ks);                                                  \
        LDA(p, ks, mh);                                                       \
        ISSUE;                                                                \
        WAITASM;                                                              \
        __builtin_amdgcn_s_barrier();                                         \
        asm volatile("s_waitcnt lgkmcnt(0)" ::: "memory");                    \
        __builtin_amdgcn_sched_barrier(0);                                    \
        __builtin_amdgcn_s_setprio(1);                                        \
        MFMA16(mh);                                                           \
        __builtin_amdgcn_s_setprio(0);                                        \
        __builtin_amdgcn_s_barrier();                                         \
    } while (0)

    // prologue: stage tile 0 fully (ks0 A,B then ks1 A,B)
    STG(0, 0, 0, 0); STG(0, 0, 1, 0); STG(1, 0, 0, 0); STG(1, 0, 1, 0);
    STG(0, 1, 0, 0); STG(0, 1, 1, 0); STG(1, 1, 0, 0); STG(1, 1, 1, 0);
    asm volatile("s_waitcnt vmcnt(4)" ::: "memory");   // tile0 ks0 resident
    __builtin_amdgcn_s_barrier();

    for (int tt = 0; tt < KST - 1; ++tt) {
        const int p = tt & 1;
        const int nx = tt + 1;
        PH(p, 0, 0, 1, { STG(0, 0, 0, nx); STG(0, 0, 1, nx); }, ((void)0));
        PH(p, 0, 1, 0, { STG(1, 0, 0, nx); STG(1, 0, 1, nx); },
           asm volatile("s_waitcnt vmcnt(4)" ::: "memory"));
        PH(p, 1, 0, 1, { STG(0, 1, 0, nx); STG(0, 1, 1, nx); }, ((void)0));
        PH(p, 1, 1, 0, { STG(1, 1, 0, nx); STG(1, 1, 1, nx); },
           asm volatile("s_waitcnt vmcnt(4)" ::: "memory"));
    }
    {   // peeled last tile: no issues; drain remaining (ks1) before ph3
        const int p = (KST - 1) & 1;
        PH(p, 0, 0, 1, ((void)0), ((void)0));
        PH(p, 0, 1, 0, ((void)0),
           asm volatile("s_waitcnt vmcnt(0)" ::: "memory"));
        PH(p, 1, 0, 1, ((void)0), ((void)0));
        PH(p, 1, 1, 0, ((void)0), ((void)0));
    }

    // epilogue: C/D layout col=lane&15, row=(lane>>4)*4+reg
#pragma unroll
    for (int mi = 0; mi < 8; ++mi) {
#pragma unroll
        for (int j = 0; j < 4; ++j) {
            int rl = wr * 128 + mi * 16 + lk * 4 + j;
            if (rl < rows) {
                int token = ord[rl];
                float* po = out + (long)token * D_OUT + y * 256 + wc * 64 + lm;
#pragma unroll
                for (int ni = 0; ni < 4; ++ni) po[ni * 16] = acc[mi][ni][j];
            }
        }
    }
#undef STG
#undef SWB
#undef LDB
#undef LDA
#undef MFMA16
#undef PH
}

// ---------- fallback (direct fp32, known-good round-1 structure) ----------

__device__ __forceinline__ int fb_a_byte(int r, int kbyte) {
    return r * 128 + (kbyte ^ ((r & 7) << 4));
}
__device__ __forceinline__ int fb_b_byte(int n, int kbyte) {
    int slot = (n ^ (n >> 2)) & 7;
    return n * 128 + (kbyte ^ (slot << 4));
}

__global__ __launch_bounds__(256, 2) void SwitchLinear_gemm_fb_kernel(
    const float* __restrict__ x, const float* __restrict__ w,
    const int* __restrict__ ws, float* __restrict__ out) {
    const int nt = ws[4];
    const int tx = blockIdx.x;
    if (tx >= nt) return;
    const int e    = ws[256 + tx];
    const int rs   = ws[328 + tx];
    const int rows = ws[400 + tx];
    const int col0 = blockIdx.y * 128;

    __shared__ __align__(16) unsigned short As[128 * 64];
    __shared__ __align__(16) unsigned short Bs[128 * 64];
    __shared__ int ord[128];

    const int t = threadIdx.x;
    if (t < 128) {
        int r = (t < rows) ? (rs + t) : rs;
        ord[t] = ws[512 + r];
    }
    __syncthreads();

    const int kq = t & 15;
    const float* pA[8];
    int rowA[8];
#pragma unroll
    for (int i = 0; i < 8; ++i) {
        int r = (t >> 4) + 16 * i;
        rowA[i] = r;
        pA[i] = x + (long)ord[r] * D_IN + kq * 4;
    }
    const float* pB[2];
    int nB[2], kbB[2];
#pragma unroll
    for (int i = 0; i < 2; ++i) {
        int u = t + 256 * i;
        int kg = u >> 5, q = u & 31;
        kbB[i] = kg * 4;
        nB[i]  = q * 4;
        pB[i]  = w + (long)e * D_IN * D_OUT + (long)(kg * 4) * D_OUT + col0 + q * 4;
    }

    const int lane = t & 63;
    const int wid  = t >> 6;
    const int wr = wid >> 1, wc = wid & 1;
    const int lm = lane & 15, lk = lane >> 4;

    f32x4 acc[4][4];
#pragma unroll
    for (int i = 0; i < 4; ++i)
#pragma unroll
        for (int j = 0; j < 4; ++j) acc[i][j] = (f32x4){0.f, 0.f, 0.f, 0.f};

    for (int k0 = 0; k0 < D_IN; k0 += 64) {
#pragma unroll
        for (int i = 0; i < 8; ++i) {
            f32x4 v = *(const f32x4*)(pA[i] + k0);
            union { __bf16 h[4]; uint2 u; } c;
            c.h[0] = (__bf16)v[0]; c.h[1] = (__bf16)v[1];
            c.h[2] = (__bf16)v[2]; c.h[3] = (__bf16)v[3];
            *(uint2*)((char*)As + fb_a_byte(rowA[i], kq * 8)) = c.u;
        }
#pragma unroll
        for (int i = 0; i < 2; ++i) {
            const float* p = pB[i] + (long)k0 * D_OUT;
            f32x4 r0 = *(const f32x4*)(p);
            f32x4 r1 = *(const f32x4*)(p + D_OUT);
            f32x4 r2 = *(const f32x4*)(p + 2 * D_OUT);
            f32x4 r3 = *(const f32x4*)(p + 3 * D_OUT);
#pragma unroll
            for (int j = 0; j < 4; ++j) {
                int n = nB[i] + j;
                union { __bf16 h[4]; uint2 u; } c;
                c.h[0] = (__bf16)r0[j]; c.h[1] = (__bf16)r1[j];
                c.h[2] = (__bf16)r2[j]; c.h[3] = (__bf16)r3[j];
                *(uint2*)((char*)Bs + fb_b_byte(n, kbB[i] * 2)) = c.u;
            }
        }
        __syncthreads();
#pragma unroll
        for (int ks = 0; ks < 2; ++ks) {
            bf16x8 a[4], b[4];
            const int kbyte = ks * 64 + lk * 16;
#pragma unroll
            for (int mi = 0; mi < 4; ++mi) {
                int r = wr * 64 + mi * 16 + lm;
                a[mi] = *(const bf16x8*)((const char*)As + fb_a_byte(r, kbyte));
            }
#pragma unroll
            for (int ni = 0; ni < 4; ++ni) {
                int n = wc * 64 + ni * 16 + lm;
                b[ni] = *(const bf16x8*)((const char*)Bs + fb_b_byte(n, kbyte));
            }
#pragma unroll
            for (int mi = 0; mi < 4; ++mi)
#pragma unroll
                for (int ni = 0; ni < 4; ++ni)
                    acc[mi][ni] = __builtin_amdgcn_mfma_f32_16x16x32_bf16(
                        a[mi], b[ni], acc[mi][ni], 0, 0, 0);
        }
        __syncthreads();
    }
#pragma unroll
    for (int mi = 0; mi < 4; ++mi) {
#pragma unroll
        for (int j = 0; j < 4; ++j) {
            int rl = wr * 64 + mi * 16 + lk * 4 + j;
            if (rl < rows) {
                int token = ord[rl];
                float* po = out + (long)token * D_OUT + col0 + wc * 64 + lm;
#pragma unroll
                for (int ni = 0; ni < 4; ++ni) po[ni * 16] = acc[mi][ni][j];
            }
        }
    }
}

extern "C" void kernel_launch(void* const* d_in, const int* in_sizes, int n_in,
                              void* d_out, int out_size, void* d_ws, size_t ws_size,
                              hipStream_t stream) {
    const float* x   = (const float*)d_in[0];
    const float* w   = (const float*)d_in[1];
    const int*   idx = (const int*)d_in[2];
    float* out = (float*)d_out;
    int*   ws  = (int*)d_ws;
    char*  wsb = (char*)d_ws;

    SwitchLinear_setup_kernel<<<1, 256, 0, stream>>>(idx, ws);
    if (ws_size >= WS_NEED2) {
        SwitchLinear_convx_kernel<<<dim3(NT2, KST), 256, 0, stream>>>(x, ws, wsb);
        SwitchLinear_convw_kernel<<<NEXP * 64 * KST, 256, 0, stream>>>(w, wsb);
        SwitchLinear_gemm_kernel<<<NT2 * NS2, 512, 0, stream>>>(wsb, ws, out);
    } else {
        dim3 grid(72, 64);
        SwitchLinear_gemm_fb_kernel<<<grid, 256, 0, stream>>>(x, w, ws, out);
    }
}